// Round 1
// baseline (2439.967 us; speedup 1.0000x reference)
//
#include <hip/hip_runtime.h>
#include <cmath>

constexpr int N = 4096;
constexpr int EDG = 131072;
constexpr float GEPS = 1e-6f;

// ---------------------------------------------------------------------------
// OUT[d,f] += sum_{j in chunk} (M[j,d]+eps)*X[j,f]   (M is N x N row-major)
template<int FC, int NJ>
__global__ void matT_pass(const float* __restrict__ M, float eps,
                          const float* __restrict__ X, float* __restrict__ OUT) {
  constexpr int FPT = FC / 4;
  constexpr int CH = N / NJ;
  const int lane = threadIdx.x & 63;
  const int wave = threadIdx.x >> 6;
  const int d = blockIdx.x * 64 + lane;
  const int j0 = blockIdx.y * CH;
  const int f0 = wave * FPT;
  float acc[FPT];
#pragma unroll
  for (int t = 0; t < FPT; ++t) acc[t] = 0.f;
  const float* Mp = M + (size_t)j0 * N + d;
  const float* Xp = X + (size_t)j0 * FC + f0;
  for (int j = 0; j < CH; ++j) {
    float m = *Mp + eps;
#pragma unroll
    for (int t = 0; t < FPT; ++t) acc[t] += m * Xp[t];
    Mp += N; Xp += FC;
  }
#pragma unroll
  for (int t = 0; t < FPT; ++t) atomicAdd(&OUT[(size_t)d * FC + f0 + t], acc[t]);
}

// OUT[r,f] += sum_{j in chunk} (M[r,j]+eps)*X[j,f]
template<int FC, int NJ>
__global__ void mat_pass(const float* __restrict__ M, float eps,
                         const float* __restrict__ X, float* __restrict__ OUT) {
  constexpr int CH = N / NJ;
  const int r = blockIdx.x * 256 + threadIdx.x;
  const int j0 = blockIdx.y * CH;
  float acc[FC];
#pragma unroll
  for (int f = 0; f < FC; ++f) acc[f] = 0.f;
  const float* Mp = M + (size_t)r * N + j0;
  const float* Xp = X + (size_t)j0 * FC;
  for (int j = 0; j < CH; j += 4) {
    float4 mv = *(const float4*)(Mp + j);
    float m0 = mv.x + eps, m1 = mv.y + eps, m2 = mv.z + eps, m3 = mv.w + eps;
    const float* xr = Xp + (size_t)j * FC;
#pragma unroll
    for (int f = 0; f < FC; ++f)
      acc[f] += m0 * xr[f] + m1 * xr[FC + f] + m2 * xr[2 * FC + f] + m3 * xr[3 * FC + f];
  }
#pragma unroll
  for (int f = 0; f < FC; ++f) atomicAdd(&OUT[(size_t)r * FC + f], acc[f]);
}

// ---------------------------------------------------------------------------
// OUT[N,F] = A[N,K] @ W[K,F]   (K in {512,64}, F in {64,32,16})
template<int F>
__global__ void mm_small(const float* __restrict__ A, const float* __restrict__ W,
                         float* __restrict__ OUT, int K) {
  constexpr int G = 256 / F;
  constexpr int RPT = 64 / G;
  __shared__ float As[64][33];
  __shared__ float Ws[32][F];
  const int t = threadIdx.x;
  const int f = t & (F - 1);
  const int rg = t / F;
  const int r0 = blockIdx.x * 64;
  float acc[RPT];
#pragma unroll
  for (int i = 0; i < RPT; ++i) acc[i] = 0.f;
  for (int k0 = 0; k0 < K; k0 += 32) {
    for (int idx = t; idx < 64 * 32; idx += 256) {
      int rr = idx >> 5, kk = idx & 31;
      As[rr][kk] = A[(size_t)(r0 + rr) * K + k0 + kk];
    }
    for (int idx = t; idx < 32 * F; idx += 256) {
      int kk = idx / F, ff = idx % F;
      Ws[kk][ff] = W[(size_t)(k0 + kk) * F + ff];
    }
    __syncthreads();
#pragma unroll
    for (int kk = 0; kk < 32; ++kk) {
      float wv = Ws[kk][f];
#pragma unroll
      for (int i = 0; i < RPT; ++i) acc[i] += As[rg * RPT + i][kk] * wv;
    }
    __syncthreads();
  }
#pragma unroll
  for (int i = 0; i < RPT; ++i)
    OUT[(size_t)(r0 + rg * RPT + i) * F + f] = acc[i];
}

// ---------------------------------------------------------------------------
__global__ void edge_gate1(const float* __restrict__ xw, const int* __restrict__ ei,
                           const float* __restrict__ b1, const float* __restrict__ w2,
                           const float* __restrict__ b2, float* __restrict__ s_out,
                           float* __restrict__ D, float* __restrict__ deg,
                           float* __restrict__ SCs) {
  const int lane = threadIdx.x & 63;
  const int wave = threadIdx.x >> 6;
  const float b1v = b1[lane];
  const float w2v = w2[lane];
  const float b2s = b2[0];
  float lsum = 0.f, lssq = 0.f;
  for (int it = 0; it < 16; ++it) {
    const int e = blockIdx.x * 64 + it * 4 + wave;
    const int s = ei[e];
    const int d = ei[EDG + e];
    float g = xw[(size_t)s * 64 + lane] - xw[(size_t)d * 64 + lane] + b1v;
    g = fmaxf(g, 0.f) * w2v;
#pragma unroll
    for (int off = 32; off; off >>= 1) g += __shfl_down(g, off);
    if (lane == 0) {
      float agg = g + b2s;
      agg *= agg;
      float sv = 1.f / (1.f + __expf(-agg));
      s_out[e] = sv;
      atomicAdd(&D[(size_t)s * N + d], sv);
      atomicAdd(&deg[d], sv);
      lsum += sv; lssq += sv * sv;
    }
  }
  __shared__ float red[8];
  if (lane == 0) { red[wave] = lsum; red[4 + wave] = lssq; }
  __syncthreads();
  if (threadIdx.x == 0) {
    atomicAdd(&SCs[0], red[0] + red[1] + red[2] + red[3]);
    atomicAdd(&SCs[1], red[4] + red[5] + red[6] + red[7]);
  }
}

__global__ void edge_gate2(const float* __restrict__ xw, const int* __restrict__ ei,
                           const float* __restrict__ b1, const float* __restrict__ w2,
                           const float* __restrict__ b2, float* __restrict__ s_out,
                           float* __restrict__ D, float* __restrict__ deg,
                           float* __restrict__ SCs) {
  const int half = threadIdx.x & 31;
  const int wi = threadIdx.x >> 5;   // 0..7 half-waves
  const float b1v = b1[half];
  const float w2v = w2[half];
  const float b2s = b2[0];
  float lsum = 0.f, lssq = 0.f;
  for (int it = 0; it < 16; ++it) {
    const int e = blockIdx.x * 128 + it * 8 + wi;
    const int s = ei[e];
    const int d = ei[EDG + e];
    float g = xw[(size_t)s * 32 + half] - xw[(size_t)d * 32 + half] + b1v;
    g = fmaxf(g, 0.f) * w2v;
#pragma unroll
    for (int off = 16; off; off >>= 1) g += __shfl_down(g, off, 32);
    if (half == 0) {
      float agg = g + b2s;
      agg *= agg;
      float sv = 1.f / (1.f + __expf(-agg));
      s_out[e] = sv;
      atomicAdd(&D[(size_t)s * N + d], sv);
      atomicAdd(&deg[d], sv);
      lsum += sv; lssq += sv * sv;
    }
  }
  __shared__ float red[16];
  if (half == 0) { red[wi] = lsum; red[8 + wi] = lssq; }
  __syncthreads();
  if (threadIdx.x == 0) {
    float a = 0.f, b = 0.f;
    for (int i = 0; i < 8; ++i) { a += red[i]; b += red[8 + i]; }
    atomicAdd(&SCs[0], a);
    atomicAdd(&SCs[1], b);
  }
}

// ---------------------------------------------------------------------------
__global__ void make_dis(const float* __restrict__ deg, float* __restrict__ dis) {
  int n = blockIdx.x * 256 + threadIdx.x;
  dis[n] = rsqrtf(deg[n] + 1.0f);   // +1 self-loop weight
}

template<int F>
__global__ void ew_scale(const float* __restrict__ h, const float* __restrict__ dis,
                         float* __restrict__ out) {
  int i = blockIdx.x * 256 + threadIdx.x;
  out[i] = dis[i / F] * h[i];
}

template<int F>
__global__ void conv_epi(const float* __restrict__ P, const float* __restrict__ h,
                         const float* __restrict__ dis, const float* __restrict__ bias,
                         float* __restrict__ out, int relu) {
  int i = blockIdx.x * 256 + threadIdx.x;
  int n = i / F, f = i % F;
  float d = dis[n];
  float v = d * P[i] + d * d * h[i] + bias[f];
  out[i] = relu ? fmaxf(v, 0.f) : v;
}

__global__ void softmax_calib(const float* __restrict__ xo, float* __restrict__ ls,
                              float* __restrict__ sm, float* __restrict__ SC) {
  const int t = threadIdx.x;
  const int r = blockIdx.x * 256 + t;
  float v[16];
  float mx = -3.0e38f, mx2 = -3.0e38f;
#pragma unroll
  for (int c = 0; c < 16; ++c) {
    v[c] = xo[(size_t)r * 16 + c];
    if (v[c] > mx) { mx2 = mx; mx = v[c]; }
    else if (v[c] > mx2) mx2 = v[c];
  }
  float se = 0.f;
#pragma unroll
  for (int c = 0; c < 16; ++c) se += expf(v[c] - mx);
  const float lse = mx + logf(se);
#pragma unroll
  for (int c = 0; c < 16; ++c) {
    float z = v[c] - lse;
    ls[(size_t)r * 16 + c] = z;
    sm[(size_t)r * 16 + c] = expf(z);
  }
  float calib = mx2 - mx;
  const int lane = t & 63, wave = t >> 6;
#pragma unroll
  for (int off = 32; off; off >>= 1) calib += __shfl_down(calib, off);
  __shared__ float red[4];
  if (lane == 0) red[wave] = calib;
  __syncthreads();
  if (t == 0) atomicAdd(&SC[4], red[0] + red[1] + red[2] + red[3]);
}

// ---------------------------------------------------------------------------
// Gram of 6 columns (stride given); optional Cholesky (upper R, G = R^T R)
__global__ void gram6(const float* __restrict__ Y, int stride,
                      double* __restrict__ G, double* __restrict__ R, int do_chol) {
  const int t = threadIdx.x;
  const int lane = t & 63, wave = t >> 6;
  float g[21];
#pragma unroll
  for (int p = 0; p < 21; ++p) g[p] = 0.f;
  for (int n = t; n < N; n += 256) {
    float y[6];
#pragma unroll
    for (int j = 0; j < 6; ++j) y[j] = Y[(size_t)n * stride + j];
    int p = 0;
#pragma unroll
    for (int i = 0; i < 6; ++i)
#pragma unroll
      for (int j = i; j < 6; ++j) g[p++] += y[i] * y[j];
  }
#pragma unroll
  for (int p = 0; p < 21; ++p)
    for (int off = 32; off; off >>= 1) g[p] += __shfl_down(g[p], off);
  __shared__ float part[4][21];
  if (lane == 0)
    for (int p = 0; p < 21; ++p) part[wave][p] = g[p];
  __syncthreads();
  if (t == 0) {
    double Gf[6][6];
    int p = 0;
    for (int i = 0; i < 6; ++i)
      for (int j = i; j < 6; ++j) {
        double val = (double)part[0][p] + part[1][p] + part[2][p] + part[3][p];
        Gf[i][j] = val; Gf[j][i] = val; G[p] = val; ++p;
      }
    if (do_chol) {
      double Rm[6][6];
      for (int i = 0; i < 6; ++i) for (int j = 0; j < 6; ++j) Rm[i][j] = 0.0;
      for (int j = 0; j < 6; ++j) {
        double s = Gf[j][j];
        for (int k = 0; k < j; ++k) s -= Rm[k][j] * Rm[k][j];
        double dj = sqrt(fmax(s, 1e-30));
        Rm[j][j] = dj;
        for (int i = j + 1; i < 6; ++i) {
          double v = Gf[j][i];
          for (int k = 0; k < j; ++k) v -= Rm[k][j] * Rm[k][i];
          Rm[j][i] = v / dj;
        }
      }
      for (int i = 0; i < 6; ++i)
        for (int j = 0; j < 6; ++j) R[i * 6 + j] = Rm[i][j];
    }
  }
}

// Y <- Y * R^{-1} (per row forward substitution)
__global__ void cholqr_apply(float* __restrict__ Y, int stride, const double* __restrict__ R) {
  __shared__ float Rs[36];
  if (threadIdx.x < 36) Rs[threadIdx.x] = (float)R[threadIdx.x];
  __syncthreads();
  int n = blockIdx.x * 256 + threadIdx.x;
  float y[6], q[6];
#pragma unroll
  for (int j = 0; j < 6; ++j) y[j] = Y[(size_t)n * stride + j];
#pragma unroll
  for (int j = 0; j < 6; ++j) {
    float s = y[j];
#pragma unroll
    for (int i = 0; i < 6; ++i)
      if (i < j) s -= q[i] * Rs[i * 6 + j];
    q[j] = s / Rs[j * 6 + j];
  }
#pragma unroll
  for (int j = 0; j < 6; ++j) Y[(size_t)n * stride + j] = q[j];
}

__global__ void jacobi6(const double* __restrict__ G, float* __restrict__ Wm,
                        float* __restrict__ rs) {
  if (threadIdx.x || blockIdx.x) return;
  double A[6][6], V[6][6];
  int p = 0;
  for (int i = 0; i < 6; ++i)
    for (int j = i; j < 6; ++j) { A[i][j] = G[p]; A[j][i] = G[p]; ++p; }
  for (int i = 0; i < 6; ++i)
    for (int j = 0; j < 6; ++j) V[i][j] = (i == j) ? 1.0 : 0.0;
  for (int sweep = 0; sweep < 30; ++sweep) {
    double off = 0.0;
    for (int i = 0; i < 6; ++i)
      for (int j = i + 1; j < 6; ++j) off += A[i][j] * A[i][j];
    if (off < 1e-24) break;
    for (int pi = 0; pi < 5; ++pi)
      for (int qi = pi + 1; qi < 6; ++qi) {
        double apq = A[pi][qi];
        if (fabs(apq) < 1e-300) continue;
        double app = A[pi][pi], aqq = A[qi][qi];
        double tau = (aqq - app) / (2.0 * apq);
        double tt = (tau >= 0.0) ? 1.0 / (tau + sqrt(1.0 + tau * tau))
                                 : 1.0 / (tau - sqrt(1.0 + tau * tau));
        double c = 1.0 / sqrt(1.0 + tt * tt), s = tt * c;
        for (int k = 0; k < 6; ++k) {
          double akp = A[k][pi], akq = A[k][qi];
          A[k][pi] = c * akp - s * akq; A[k][qi] = s * akp + c * akq;
        }
        for (int k = 0; k < 6; ++k) {
          double apk = A[pi][k], aqk = A[qi][k];
          A[pi][k] = c * apk - s * aqk; A[qi][k] = s * apk + c * aqk;
        }
        for (int k = 0; k < 6; ++k) {
          double vkp = V[k][pi], vkq = V[k][qi];
          V[k][pi] = c * vkp - s * vkq; V[k][qi] = s * vkp + c * vkq;
        }
      }
  }
  int idx[6] = {0, 1, 2, 3, 4, 5};
  for (int a = 0; a < 5; ++a)
    for (int b = 0; b < 5 - a; ++b)
      if (A[idx[b]][idx[b]] < A[idx[b + 1]][idx[b + 1]]) {
        int tmp = idx[b]; idx[b] = idx[b + 1]; idx[b + 1] = tmp;
      }
  for (int k = 0; k < 6; ++k) {
    double lam = A[idx[k]][idx[k]];
    rs[k] = (float)(1.0 / sqrt(fmax(lam, 1e-30)));
    for (int j = 0; j < 6; ++j) Wm[j * 6 + k] = (float)V[j][idx[k]];
  }
}

// V8[n,k] = (sum_j Bt[n,j]*Wm[j,k]) * rs[k];  cols 6,7 zeroed
__global__ void v_scale(const float* __restrict__ Bt, const float* __restrict__ Wm,
                        const float* __restrict__ rs, float* __restrict__ V8) {
  __shared__ float Ws[36], rss[6];
  if (threadIdx.x < 36) Ws[threadIdx.x] = Wm[threadIdx.x];
  if (threadIdx.x < 6) rss[threadIdx.x] = rs[threadIdx.x];
  __syncthreads();
  int n = blockIdx.x * 256 + threadIdx.x;
  float b[6];
#pragma unroll
  for (int j = 0; j < 6; ++j) b[j] = Bt[(size_t)n * 8 + j];
#pragma unroll
  for (int k = 0; k < 6; ++k) {
    float s = 0.f;
#pragma unroll
    for (int j = 0; j < 6; ++j) s += b[j] * Ws[j * 6 + k];
    V8[(size_t)n * 8 + k] = s * rss[k];
  }
  V8[(size_t)n * 8 + 6] = 0.f;
  V8[(size_t)n * 8 + 7] = 0.f;
}

__global__ void pad8(const float* __restrict__ src, float* __restrict__ dst) {
  int n = blockIdx.x * 256 + threadIdx.x;
#pragma unroll
  for (int k = 0; k < 6; ++k) dst[(size_t)n * 8 + k] = src[(size_t)n * 6 + k];
  dst[(size_t)n * 8 + 6] = 0.f;
  dst[(size_t)n * 8 + 7] = 0.f;
}

__global__ void pack3(const float* __restrict__ V8, float* __restrict__ W) {
  int n = blockIdx.x * 256 + threadIdx.x;
  W[(size_t)n * 4 + 0] = V8[(size_t)n * 8 + 0];
  W[(size_t)n * 4 + 1] = V8[(size_t)n * 8 + 1];
  W[(size_t)n * 4 + 2] = V8[(size_t)n * 8 + 2];
  W[(size_t)n * 4 + 3] = 0.f;
}

// out[n*FCpad+t] = base[n]*prod_{bit b of t} U[b*N+n], t<nterms; zero pad
__global__ void build_W(float* __restrict__ out, int FCpad, int nterms, int nu,
                        const float* __restrict__ base, int bstride, int boff,
                        const float* __restrict__ U, const float* __restrict__ SC,
                        int rs_idx) {
  int n = blockIdx.x * 256 + threadIdx.x;
  float bv = base[(size_t)n * bstride + boff];
  if (rs_idx >= 0) bv *= rsqrtf(SC[rs_idx]);
  float uv[3];
  for (int b = 0; b < 3; ++b) uv[b] = (b < nu) ? U[(size_t)b * N + n] : 0.f;
  for (int t = 0; t < FCpad; ++t) {
    float v = 0.f;
    if (t < nterms) {
      v = bv;
      for (int b = 0; b < nu; ++b)
        if ((t >> b) & 1) v *= uv[b];
    }
    out[(size_t)n * FCpad + t] = v;
  }
}

// y[n] = sum_t (-1)^popc(t) * (prod_{b in t} U_b[n]) * Y[n*FCpad+t]
__global__ void combine_y(float* __restrict__ y, const float* __restrict__ Y,
                          int FCpad, int nterms, int nu, const float* __restrict__ U) {
  int n = blockIdx.x * 256 + threadIdx.x;
  float uv[3];
  for (int b = 0; b < 3; ++b) uv[b] = (b < nu) ? U[(size_t)b * N + n] : 0.f;
  float s = 0.f;
  for (int t = 0; t < nterms; ++t) {
    float w = Y[(size_t)n * FCpad + t];
    int pc = 0;
    for (int b = 0; b < nu; ++b)
      if ((t >> b) & 1) { w *= uv[b]; ++pc; }
    s += (pc & 1) ? -w : w;
  }
  y[n] = s;
}

__global__ void cols_sumsq(const float* __restrict__ X, int stride, int ncols,
                           float* __restrict__ SC, int idx0) {
  const int t = threadIdx.x;
  const int lane = t & 63, wave = t >> 6;
  const int n = blockIdx.x * 256 + t;
  float a[8];
#pragma unroll
  for (int c = 0; c < 8; ++c) a[c] = 0.f;
  for (int c = 0; c < ncols; ++c) {
    float v = X[(size_t)n * stride + c];
    a[c] = v * v;
  }
  for (int c = 0; c < ncols; ++c)
    for (int off = 32; off; off >>= 1) a[c] += __shfl_down(a[c], off);
  __shared__ float part[4][8];
  if (lane == 0)
    for (int c = 0; c < ncols; ++c) part[wave][c] = a[c];
  __syncthreads();
  if (t == 0)
    for (int c = 0; c < ncols; ++c)
      atomicAdd(&SC[idx0 + c], part[0][c] + part[1][c] + part[2][c] + part[3][c]);
}

__global__ void vec_dot(const float* __restrict__ A, int sa, int oa,
                        const float* __restrict__ B, int sb, int ob,
                        float* __restrict__ SC, int idx) {
  const int t = threadIdx.x;
  const int lane = t & 63, wave = t >> 6;
  const int n = blockIdx.x * 256 + t;
  float v = A[(size_t)n * sa + oa] * B[(size_t)n * sb + ob];
  for (int off = 32; off; off >>= 1) v += __shfl_down(v, off);
  __shared__ float part[4];
  if (lane == 0) part[wave] = v;
  __syncthreads();
  if (t == 0) atomicAdd(&SC[idx], part[0] + part[1] + part[2] + part[3]);
}

__global__ void vscale1(float* __restrict__ out, const float* __restrict__ in,
                        int stride, int off, const float* __restrict__ SC, int rs_idx) {
  int n = blockIdx.x * 256 + threadIdx.x;
  float v = in[(size_t)n * stride + off];
  if (rs_idx >= 0) v *= rsqrtf(SC[rs_idx]);
  out[n] = v;
}

__global__ void axpy3(float* __restrict__ out, const float* __restrict__ Y, int stride,
                      int off, const float* __restrict__ q0, const float* __restrict__ q1,
                      const float* __restrict__ q2, const float* __restrict__ SC,
                      int c0, int c1, int c2, int np, int coef_rs, int out_rs) {
  int n = blockIdx.x * 256 + threadIdx.x;
  float crs = (coef_rs >= 0) ? rsqrtf(SC[coef_rs]) : 1.f;
  float s = Y[(size_t)n * stride + off];
  if (np > 0) s -= SC[c0] * crs * q0[n];
  if (np > 1) s -= SC[c1] * crs * q1[n];
  if (np > 2) s -= SC[c2] * crs * q2[n];
  if (out_rs >= 0) s *= rsqrtf(SC[out_rs]);
  out[n] = s;
}

__global__ void nuc_accum(float* __restrict__ SC, int mode, int z0, int nterms,
                          int ny0, int dps, int nd) {
  if (threadIdx.x || blockIdx.x) return;
  float add = 0.f;
  if (mode == 0) {
    for (int k = 0; k < 3; ++k) add += sqrtf(fabsf(SC[z0 + k] / SC[ny0 + k]));
  } else if (mode == 1) {
    float vmv = 0.f;
    for (int t = 0; t < nterms; ++t) {
      int pc = __popc(t);
      vmv += (pc & 1) ? -SC[z0 + t] : SC[z0 + t];
    }
    add = sqrtf(fabsf(vmv / SC[ny0]));
  } else {
    float vmv = SC[z0];
    for (int t = 0; t < nd; ++t) vmv -= SC[dps + 2 * t] * SC[dps + 2 * t + 1];
    add = sqrtf(fabsf(vmv / SC[ny0]));
  }
  SC[5] += add;
}

__global__ void finalize_k(const float* __restrict__ SC, float* __restrict__ out) {
  if (threadIdx.x || blockIdx.x) return;
  const float Ef = (float)EDG;
  float m1 = SC[0] / Ef, v1 = SC[1] / Ef - m1 * m1;
  float m2 = SC[2] / Ef, v2 = SC[3] / Ef - m2 * m2;
  out[131072] = 0.01f * (v1 + v2) + 0.01f * SC[5];
  out[393217] = SC[4] / (float)N;
}

// ---------------------------------------------------------------------------
extern "C" void kernel_launch(void* const* d_in, const int* in_sizes, int n_in,
                              void* d_out, int out_size, void* d_ws, size_t ws_size,
                              hipStream_t stream) {
  const float* x      = (const float*)d_in[0];
  const int*   ei     = (const int*)  d_in[1];
  const float* gcn1_w = (const float*)d_in[2];
  const float* gcn1_b = (const float*)d_in[3];
  const float* gcn2_w = (const float*)d_in[4];
  const float* gcn2_b = (const float*)d_in[5];
  const float* p1w1   = (const float*)d_in[6];
  const float* p1b1   = (const float*)d_in[7];
  const float* p1w2   = (const float*)d_in[8];
  const float* p1b2   = (const float*)d_in[9];
  const float* p2w1   = (const float*)d_in[10];
  const float* p2b1   = (const float*)d_in[11];
  const float* p2w2   = (const float*)d_in[12];
  const float* p2b2   = (const float*)d_in[13];
  const float* omega1 = (const float*)d_in[14];
  const float* omega2 = (const float*)d_in[15];
  float* out = (float*)d_out;

  float* ws = (float*)d_ws;
  size_t o = 0;
  auto alloc = [&](size_t nf) { float* p = ws + o; o += nf; return p; };
  float* D    = alloc((size_t)N * N);
  float* xw1  = alloc((size_t)N * 64);
  float* h1   = alloc((size_t)N * 64);
  float* xh   = alloc((size_t)N * 64);
  float* x1   = alloc((size_t)N * 64);
  float* P    = alloc((size_t)N * 64);
  float* x1w  = alloc((size_t)N * 32);
  float* h2   = alloc((size_t)N * 16);
  float* xh2  = alloc((size_t)N * 16);
  float* xout = alloc((size_t)N * 16);
  float* deg1 = alloc(N);
  float* dis1 = alloc(N);
  float* deg2 = alloc(N);
  float* dis2 = alloc(N);
  float* Qb8  = alloc((size_t)N * 8);
  float* Zi8  = alloc((size_t)N * 8);
  float* Bt8  = alloc((size_t)N * 8);
  float* V8   = alloc((size_t)N * 8);
  float* W8   = alloc((size_t)N * 8);
  float* T8   = alloc((size_t)N * 8);
  float* Y8   = alloc((size_t)N * 8);
  float* Zz8  = alloc((size_t)N * 8);
  float* P8   = alloc((size_t)N * 8);
  float* yv   = alloc(N);
  float* Uv   = alloc((size_t)3 * N);
  float* Pv   = alloc((size_t)3 * N);
  float* SC   = alloc(256);
  float* SMF  = alloc(64);            // Wm[36] + rs[6]
  o = (o + 1) & ~(size_t)1;
  double* Gd = (double*)(ws + o); o += 48;   // 21 doubles (padded)
  double* Rd = (double*)(ws + o); o += 80;   // 36 doubles (padded)
  if (ws_size < o * sizeof(float)) return;   // insufficient scratch -> loud failure

  auto zero = [&](float* p, size_t nf) {
    hipMemsetAsync(p, 0, nf * sizeof(float), stream);
  };

  // SC slots
  enum {
    A_NY = 8,  A_Z = 11,
    A_NY3 = 14, A_Z3 = 15,
    A_NY4 = 17, A_Z4 = 18,
    A_NY5 = 22, A_Z5 = 23,
    B_NY = 34, B_Z = 37,
    B_C3 = 40, B_NY3 = 41, B_ZZ3 = 42, B_DP3 = 43,
    B_C4 = 45, B_NY4 = 47, B_ZZ4 = 48, B_DP4 = 49,
    B_C5 = 53, B_NY5 = 56, B_ZZ5 = 57, B_DP5 = 58
  };

  auto run_svd = [&](const float* omega) {
    pad8<<<16, 256, 0, stream>>>(omega, W8);
    zero(Qb8, (size_t)N * 8);
    mat_pass<8, 16><<<dim3(16, 16), 256, 0, stream>>>(D, GEPS, W8, Qb8);
    gram6<<<1, 256, 0, stream>>>(Qb8, 8, Gd, Rd, 1);
    cholqr_apply<<<16, 256, 0, stream>>>(Qb8, 8, Rd);
    for (int itp = 0; itp < 2; ++itp) {
      zero(Zi8, (size_t)N * 8);
      matT_pass<8, 8><<<dim3(64, 8), 256, 0, stream>>>(D, GEPS, Qb8, Zi8);
      gram6<<<1, 256, 0, stream>>>(Zi8, 8, Gd, Rd, 1);
      cholqr_apply<<<16, 256, 0, stream>>>(Zi8, 8, Rd);
      zero(Qb8, (size_t)N * 8);
      mat_pass<8, 16><<<dim3(16, 16), 256, 0, stream>>>(D, GEPS, Zi8, Qb8);
      gram6<<<1, 256, 0, stream>>>(Qb8, 8, Gd, Rd, 1);
      cholqr_apply<<<16, 256, 0, stream>>>(Qb8, 8, Rd);
    }
    zero(Bt8, (size_t)N * 8);
    matT_pass<8, 8><<<dim3(64, 8), 256, 0, stream>>>(D, GEPS, Qb8, Bt8);
    gram6<<<1, 256, 0, stream>>>(Bt8, 8, Gd, nullptr, 0);
    jacobi6<<<1, 1, 0, stream>>>(Gd, SMF, SMF + 36);
    v_scale<<<16, 256, 0, stream>>>(Bt8, SMF, SMF + 36, V8);
  };

  auto nuc_batch3 = [&](int nyIdx, int zIdx) {
    pack3<<<16, 256, 0, stream>>>(V8, W8);
    zero(T8, (size_t)N * 4);
    matT_pass<4, 8><<<dim3(64, 8), 256, 0, stream>>>(D, GEPS, W8, T8);
    zero(Y8, (size_t)N * 4);
    mat_pass<4, 16><<<dim3(16, 16), 256, 0, stream>>>(D, GEPS, T8, Y8);
    cols_sumsq<<<16, 256, 0, stream>>>(Y8, 4, 3, SC, nyIdx);
    zero(Zz8, (size_t)N * 4);
    matT_pass<4, 8><<<dim3(64, 8), 256, 0, stream>>>(D, GEPS, Y8, Zz8);
    cols_sumsq<<<16, 256, 0, stream>>>(Zz8, 4, 3, SC, zIdx);
    nuc_accum<<<1, 1, 0, stream>>>(SC, 0, zIdx, 3, nyIdx, 0, 0);
    vscale1<<<16, 256, 0, stream>>>(Uv, Y8, 4, 2, SC, nyIdx + 2);  // u2
  };

  // ===================== init =====================
  zero(D, (size_t)N * N);
  zero(deg1, N);
  zero(deg2, N);
  zero(SC, 256);

  // ===================== graph 1: gate + conv =====================
  mm_small<64><<<64, 256, 0, stream>>>(x, p1w1, xw1, 512);
  edge_gate1<<<2048, 256, 0, stream>>>(xw1, ei, p1b1, p1w2, p1b2,
                                       out + 131073, D, deg1, SC + 0);
  make_dis<<<16, 256, 0, stream>>>(deg1, dis1);
  mm_small<64><<<64, 256, 0, stream>>>(x, gcn1_w, h1, 512);
  ew_scale<64><<<1024, 256, 0, stream>>>(h1, dis1, xh);
  zero(P, (size_t)N * 64);
  matT_pass<64, 4><<<dim3(64, 4), 256, 0, stream>>>(D, 0.f, xh, P);
  conv_epi<64><<<1024, 256, 0, stream>>>(P, h1, dis1, gcn1_b, x1, 1);

  // ===================== SVD1 + nuc1 (elementwise deflation) =====================
  run_svd(omega1);
  nuc_batch3(A_NY, A_Z);
  {
    const int NYk[3] = {A_NY3, A_NY4, A_NY5};
    const int Zk[3]  = {A_Z3, A_Z4, A_Z5};
    for (int k = 3; k <= 5; ++k) {
      int nu = k - 2, nt = 1 << nu;
      int ny = NYk[k - 3], zz = Zk[k - 3];
      if (k < 5) {
        build_W<<<16, 256, 0, stream>>>(W8, 4, nt, nu, V8, 8, k, Uv, SC, -1);
        zero(T8, (size_t)N * 4);
        matT_pass<4, 8><<<dim3(64, 8), 256, 0, stream>>>(D, GEPS, W8, T8);
        zero(Y8, (size_t)N * 4);
        mat_pass<4, 16><<<dim3(16, 16), 256, 0, stream>>>(D, GEPS, T8, Y8);
        combine_y<<<16, 256, 0, stream>>>(yv, Y8, 4, nt, nu, Uv);
        cols_sumsq<<<16, 256, 0, stream>>>(yv, 1, 1, SC, ny);
        build_W<<<16, 256, 0, stream>>>(W8, 4, nt, nu, yv, 1, 0, Uv, SC, -1);
        zero(Zz8, (size_t)N * 4);
        matT_pass<4, 8><<<dim3(64, 8), 256, 0, stream>>>(D, GEPS, W8, Zz8);
        cols_sumsq<<<16, 256, 0, stream>>>(Zz8, 4, nt, SC, zz);
      } else {
        build_W<<<16, 256, 0, stream>>>(W8, 8, nt, nu, V8, 8, k, Uv, SC, -1);
        zero(T8, (size_t)N * 8);
        matT_pass<8, 8><<<dim3(64, 8), 256, 0, stream>>>(D, GEPS, W8, T8);
        zero(Y8, (size_t)N * 8);
        mat_pass<8, 16><<<dim3(16, 16), 256, 0, stream>>>(D, GEPS, T8, Y8);
        combine_y<<<16, 256, 0, stream>>>(yv, Y8, 8, nt, nu, Uv);
        cols_sumsq<<<16, 256, 0, stream>>>(yv, 1, 1, SC, ny);
        build_W<<<16, 256, 0, stream>>>(W8, 8, nt, nu, yv, 1, 0, Uv, SC, -1);
        zero(Zz8, (size_t)N * 8);
        matT_pass<8, 8><<<dim3(64, 8), 256, 0, stream>>>(D, GEPS, W8, Zz8);
        cols_sumsq<<<16, 256, 0, stream>>>(Zz8, 8, nt, SC, zz);
      }
      nuc_accum<<<1, 1, 0, stream>>>(SC, 1, zz, nt, ny, 0, 0);
      if (k < 5)
        vscale1<<<16, 256, 0, stream>>>(Uv + (size_t)(k - 2) * N, yv, 1, 0, SC, ny);
    }
  }

  // ===================== graph 2: gate + conv + outputs =====================
  zero(D, (size_t)N * N);
  mm_small<32><<<64, 256, 0, stream>>>(x1, p2w1, x1w, 64);
  edge_gate2<<<1024, 256, 0, stream>>>(x1w, ei, p2b1, p2w2, p2b2,
                                       out + 262145, D, deg2, SC + 2);
  make_dis<<<16, 256, 0, stream>>>(deg2, dis2);
  mm_small<16><<<64, 256, 0, stream>>>(x1, gcn2_w, h2, 64);
  ew_scale<16><<<256, 256, 0, stream>>>(h2, dis2, xh2);
  zero(P, (size_t)N * 16);
  matT_pass<16, 4><<<dim3(64, 4), 256, 0, stream>>>(D, 0.f, xh2, P);
  conv_epi<16><<<256, 256, 0, stream>>>(P, h2, dis2, gcn2_b, xout, 0);
  softmax_calib<<<16, 256, 0, stream>>>(xout, out, out + 65536, SC);

  // ===================== SVD2 + nuc2 (rank-1 deflation) =====================
  run_svd(omega2);
  nuc_batch3(B_NY, B_Z);
  // p2 = A @ (Z col2 * rsqrt(ny2))
  build_W<<<16, 256, 0, stream>>>(W8, 4, 1, 0, Zz8, 4, 2, nullptr, SC, B_NY + 2);
  zero(P8, (size_t)N * 4);
  mat_pass<4, 16><<<dim3(16, 16), 256, 0, stream>>>(D, GEPS, W8, P8);
  vscale1<<<16, 256, 0, stream>>>(Pv, P8, 4, 0, SC, -1);
  {
    const int Ck[3]  = {B_C3, B_C4, B_C5};
    const int NYk[3] = {B_NY3, B_NY4, B_NY5};
    const int ZZk[3] = {B_ZZ3, B_ZZ4, B_ZZ5};
    const int DPk[3] = {B_DP3, B_DP4, B_DP5};
    for (int k = 3; k <= 5; ++k) {
      int nd = k - 2;
      int C = Ck[k - 3], ny = NYk[k - 3], zz = ZZk[k - 3], dp = DPk[k - 3];
      for (int t = 0; t < nd; ++t)
        vec_dot<<<16, 256, 0, stream>>>(Uv + (size_t)t * N, 1, 0, V8, 8, k, SC, C + t);
      build_W<<<16, 256, 0, stream>>>(W8, 4, 1, 0, V8, 8, k, nullptr, SC, -1);
      zero(T8, (size_t)N * 4);
      matT_pass<4, 8><<<dim3(64, 8), 256, 0, stream>>>(D, GEPS, W8, T8);
      zero(Y8, (size_t)N * 4);
      mat_pass<4, 16><<<dim3(16, 16), 256, 0, stream>>>(D, GEPS, T8, Y8);
      axpy3<<<16, 256, 0, stream>>>(yv, Y8, 4, 0, Pv, Pv + N, Pv + 2 * N,
                                    SC, C, C + 1, C + 2, nd, -1, -1);
      cols_sumsq<<<16, 256, 0, stream>>>(yv, 1, 1, SC, ny);
      build_W<<<16, 256, 0, stream>>>(W8, 4, 1, 0, yv, 1, 0, nullptr, SC, -1);
      zero(Zz8, (size_t)N * 4);
      matT_pass<4, 8><<<dim3(64, 8), 256, 0, stream>>>(D, GEPS, W8, Zz8);
      cols_sumsq<<<16, 256, 0, stream>>>(Zz8, 4, 1, SC, zz);
      for (int t = 0; t < nd; ++t) {
        vec_dot<<<16, 256, 0, stream>>>(yv, 1, 0, Pv + (size_t)t * N, 1, 0, SC, dp + 2 * t);
        vec_dot<<<16, 256, 0, stream>>>(Uv + (size_t)t * N, 1, 0, yv, 1, 0, SC, dp + 2 * t + 1);
      }
      nuc_accum<<<1, 1, 0, stream>>>(SC, 2, zz, 0, ny, dp, nd);
      if (k < 5) {
        vscale1<<<16, 256, 0, stream>>>(Uv + (size_t)(k - 2) * N, yv, 1, 0, SC, ny);
        build_W<<<16, 256, 0, stream>>>(W8, 4, 1, 0, Zz8, 4, 0, nullptr, SC, ny);
        zero(P8, (size_t)N * 4);
        mat_pass<4, 16><<<dim3(16, 16), 256, 0, stream>>>(D, GEPS, W8, P8);
        axpy3<<<16, 256, 0, stream>>>(Pv + (size_t)(k - 2) * N, P8, 4, 0,
                                      Pv, Pv + N, Pv + 2 * N,
                                      SC, dp + 1, dp + 3, dp + 5, nd, ny, -1);
      }
    }
  }

  finalize_k<<<1, 1, 0, stream>>>(SC, out);
}